// Round 6
// baseline (1297.582 us; speedup 1.0000x reference)
//
#include <hip/hip_runtime.h>
#include <hip/hip_bf16.h>

#define NN 20000
#define EE 320000
#define HD 128   // hidden

typedef _Float16 half8 __attribute__((ext_vector_type(8)));
typedef float floatx4 __attribute__((ext_vector_type(4)));

__device__ __forceinline__ float silu_f(float x){ return x / (1.f + __expf(-x)); }

// edge_index dtype probe (int64-as-int32 has zero odd words); verified int32 on this
// harness (r0 vs r1 identical), but the probe is free and robust.
__device__ __forceinline__ bool ei_is64(const int* __restrict__ ei){
  return (ei[1] | ei[3] | ei[5] | ei[7]) == 0;
}
__device__ __forceinline__ int ei_src(const int* __restrict__ ei, int e, bool is64){
  return is64 ? ei[2*(size_t)e] : ei[e];
}
__device__ __forceinline__ int ei_dst(const int* __restrict__ ei, int e, bool is64){
  return is64 ? ei[2*(size_t)EE + 2*(size_t)e] : ei[EE + e];
}

__global__ __launch_bounds__(256) void sentinel_kernel(float* __restrict__ out, int n, float val){
  int i = blockIdx.x*256 + threadIdx.x;
  if (i < n) out[i] = val;
}

// ---------------- W1 packing: MFMA B-fragment fp16 layout ----------------
// w1p[l*36864 + ((ks*8+cb)*64+lane)*8 + j] = W1[l][ks*32+(lane>>4)*8+j][cb*16+(lane&15)], 0 if k>=259
__global__ __launch_bounds__(256) void pack_w1_kernel(const float* __restrict__ w1,
                                                      _Float16* __restrict__ w1p){
  int idx = blockIdx.x*256 + threadIdx.x;      // 6*36864 = 221184 total
  int j    = idx & 7;
  int lane = (idx >> 3) & 63;
  int rest = idx >> 9;          // l*72 + ks*8 + cb
  int cb   = rest & 7;
  int rest2= rest >> 3;         // l*9 + ks
  int ks   = rest2 % 9;
  int l    = rest2 / 9;
  int k = ks*32 + (lane>>4)*8 + j;
  int n = cb*16 + (lane&15);
  float v = (k < 259) ? w1[(size_t)l*259*128 + (size_t)k*128 + n] : 0.f;
  w1p[idx] = (_Float16)v;
}

// ---------------- degree ----------------
__global__ __launch_bounds__(256) void deg_kernel(const int* __restrict__ ei, float* __restrict__ deg){
  int e = blockIdx.x*256 + threadIdx.x;   // grid exact: EE/256
  bool is64 = ei_is64(ei);
  unsafeAtomicAdd(&deg[ei_dst(ei, e, is64)], 1.f);   // HW fp32 atomic works on d_ws (r1==r2)
}
__global__ __launch_bounds__(256) void invd_kernel(const float* __restrict__ deg, float* __restrict__ invd){
  int n = blockIdx.x*256 + threadIdx.x;
  if (n < NN){ float d = deg[n]; invd[n] = d > 0.f ? 1.f/d : 0.f; }
}

// ---------------- encoder: x(N,14) -> h(N,128) fp32 + fp16 ----------------
__global__ __launch_bounds__(128) void encoder_kernel(
    const float* __restrict__ x, const float* __restrict__ w1, const float* __restrict__ b1,
    const float* __restrict__ w2, const float* __restrict__ b2,
    float* __restrict__ h, _Float16* __restrict__ hh)
{
  __shared__ float xs[16][14];
  __shared__ float s1[16][128];
  const int n0 = blockIdx.x*16;
  const int tid = threadIdx.x;
  for (int idx=tid; idx<224; idx+=128){
    int i = idx/14, k = idx%14;
    xs[i][k] = x[(size_t)(n0+i)*14 + k];
  }
  __syncthreads();
  const int o = tid;
  float acc[16];
  float bv = b1[o];
  #pragma unroll
  for (int i=0;i<16;++i) acc[i] = bv;
  for (int k=0;k<14;++k){
    float w = w1[k*128+o];
    #pragma unroll
    for (int i=0;i<16;++i) acc[i] += xs[i][k]*w;
  }
  #pragma unroll
  for (int i=0;i<16;++i) s1[i][o] = silu_f(acc[i]);
  __syncthreads();
  float bv2 = b2[o];
  #pragma unroll
  for (int i=0;i<16;++i) acc[i] = bv2;
  for (int k=0;k<128;k+=4){
    float w0=w2[(k+0)*128+o], w1v=w2[(k+1)*128+o], w2v=w2[(k+2)*128+o], w3v=w2[(k+3)*128+o];
    #pragma unroll
    for (int i=0;i<16;++i){
      float4 sv = *(const float4*)&s1[i][k];
      acc[i] += sv.x*w0 + sv.y*w1v + sv.z*w2v + sv.w*w3v;
    }
  }
  #pragma unroll
  for (int i=0;i<16;++i){
    size_t off = (size_t)(n0+i)*HD + o;
    h[off] = acc[i];
    hh[off] = (_Float16)acc[i];
  }
}

// ---------------- edge kernel: GEMM1 (MFMA f16, K=288 padded) + silu + atomic scatter ----------------
// block = 256 thr = 4 waves; wave = 32 edges (2 row-blocks of 16); 8 col-blocks of 16
__global__ __launch_bounds__(256) void edge_kernel(
    const _Float16* __restrict__ hh, const int* __restrict__ ei,
    const float* __restrict__ eattr, const _Float16* __restrict__ w1p,
    const float* __restrict__ b1, float* __restrict__ S)
{
  const int tid = threadIdx.x;
  const int wv  = tid >> 6;
  const int ln  = tid & 63;
  const int q   = ln >> 4;
  const int m   = ln & 15;
  const int ebase = blockIdx.x*128 + wv*32;
  const int e0 = ebase + m;        // row m of row-block 0
  const int e1 = e0 + 16;          // row m of row-block 1
  const bool is64 = ei_is64(ei);
  const int s0 = ei_src(ei, e0, is64), s1 = ei_src(ei, e1, is64);
  const int d0 = ei_dst(ei, e0, is64), d1 = ei_dst(ei, e1, is64);

  const _Float16* p0d = hh + (size_t)d0*HD + q*8;
  const _Float16* p0s = hh + (size_t)s0*HD + q*8;
  const _Float16* p1d = hh + (size_t)d1*HD + q*8;
  const _Float16* p1s = hh + (size_t)s1*HD + q*8;

  floatx4 acc[2][8];
  #pragma unroll
  for (int a=0;a<2;++a)
    #pragma unroll
    for (int c=0;c<8;++c) acc[a][c] = (floatx4){0.f,0.f,0.f,0.f};

  #pragma unroll
  for (int ks=0; ks<8; ++ks){
    const _Float16* a0p = (ks<4 ? p0d : p0s) + (ks&3)*32;
    const _Float16* a1p = (ks<4 ? p1d : p1s) + (ks&3)*32;
    half8 a0 = *(const half8*)a0p;
    half8 a1 = *(const half8*)a1p;
    const _Float16* wb = w1p + (size_t)(ks*8*64 + ln)*8;
    #pragma unroll
    for (int cb=0; cb<8; ++cb){
      half8 b = *(const half8*)(wb + cb*512);
      acc[0][cb] = __builtin_amdgcn_mfma_f32_16x16x32_f16(a0, b, acc[0][cb], 0,0,0);
      acc[1][cb] = __builtin_amdgcn_mfma_f32_16x16x32_f16(a1, b, acc[1][cb], 0,0,0);
    }
  }
  { // tail K-step 8: k=256..287 -> [ea0,ea1,ea2,0,...] for quad 0, zeros elsewhere
    half8 a0, a1;
    #pragma unroll
    for (int j=0;j<8;++j){ a0[j] = (_Float16)0.f; a1[j] = (_Float16)0.f; }
    if (q == 0){
      a0[0]=(_Float16)eattr[(size_t)e0*3+0]; a0[1]=(_Float16)eattr[(size_t)e0*3+1]; a0[2]=(_Float16)eattr[(size_t)e0*3+2];
      a1[0]=(_Float16)eattr[(size_t)e1*3+0]; a1[1]=(_Float16)eattr[(size_t)e1*3+1]; a1[2]=(_Float16)eattr[(size_t)e1*3+2];
    }
    const _Float16* wb = w1p + (size_t)(8*8*64 + ln)*8;
    #pragma unroll
    for (int cb=0; cb<8; ++cb){
      half8 b = *(const half8*)(wb + cb*512);
      acc[0][cb] = __builtin_amdgcn_mfma_f32_16x16x32_f16(a0, b, acc[0][cb], 0,0,0);
      acc[1][cb] = __builtin_amdgcn_mfma_f32_16x16x32_f16(a1, b, acc[1][cb], 0,0,0);
    }
  }
  // epilogue: C layout col = cb*16 + (lane&15), row(edge) = rb*16 + q*4 + r
  int dr0[4], dr1[4];
  #pragma unroll
  for (int r=0;r<4;++r){
    dr0[r] = __shfl(d0, q*4+r);   // lane (q*4+r) holds dst[ebase + q*4+r]
    dr1[r] = __shfl(d1, q*4+r);
  }
  #pragma unroll
  for (int cb=0; cb<8; ++cb){
    const int c = cb*16 + m;
    const float bv = b1[c];
    #pragma unroll
    for (int r=0;r<4;++r){
      float v0 = silu_f(acc[0][cb][r] + bv);
      unsafeAtomicAdd(&S[(size_t)dr0[r]*HD + c], v0);
      float v1 = silu_f(acc[1][cb][r] + bv);
      unsafeAtomicAdd(&S[(size_t)dr1[r]*HD + c], v1);
    }
  }
}

// ---------------- node update: h += (S*invd)·W2 + b2 (fp32), refresh h_fp16, zero S ----------------
__global__ __launch_bounds__(128) void node_kernel(
    const float* __restrict__ w2, const float* __restrict__ b2,
    float* __restrict__ S, const float* __restrict__ invd,
    float* __restrict__ h, _Float16* __restrict__ hh)
{
  __shared__ float t[16][128];
  const int n0 = blockIdx.x*16;
  const int tid = threadIdx.x;
  for (int idx=tid; idx<2048; idx+=128){
    int i = idx >> 7, k = idx & 127;
    size_t off = (size_t)(n0+i)*HD + k;
    t[i][k] = S[off] * invd[n0+i];
    S[off] = 0.f;                 // reset for next layer
  }
  __syncthreads();
  const int o = tid;
  float acc[16];
  const float bv = b2[o];
  #pragma unroll
  for (int i=0;i<16;++i) acc[i] = (invd[n0+i] > 0.f) ? bv : 0.f;
  for (int k=0;k<128;k+=4){
    float w0 = w2[(k+0)*128+o];
    float w1v= w2[(k+1)*128+o];
    float w2v= w2[(k+2)*128+o];
    float w3v= w2[(k+3)*128+o];
    #pragma unroll
    for (int i=0;i<16;++i){
      float4 tv = *(const float4*)&t[i][k];
      acc[i] += tv.x*w0 + tv.y*w1v + tv.z*w2v + tv.w*w3v;
    }
  }
  #pragma unroll
  for (int i=0;i<16;++i){
    size_t off = (size_t)(n0+i)*HD + o;
    float hv = h[off] + acc[i];
    h[off] = hv;
    hh[off] = (_Float16)hv;
  }
}

// ---------------- decoder: 128 ->(silu) 128 ->(silu) 64 -> 9 ----------------
__global__ __launch_bounds__(128) void decoder_kernel(
    const float* __restrict__ h,
    const float* __restrict__ w1, const float* __restrict__ b1,
    const float* __restrict__ w2, const float* __restrict__ b2,
    const float* __restrict__ w3, const float* __restrict__ b3,
    float* __restrict__ out)
{
  __shared__ float ht[16][128];
  __shared__ float s1[16][128];
  __shared__ float s2[16][64];
  const int n0 = blockIdx.x*16;
  const int tid = threadIdx.x;
  for (int idx=tid; idx<2048; idx+=128){
    int i = idx>>7, k = idx&127;
    ht[i][k] = h[(size_t)(n0+i)*HD + k];
  }
  __syncthreads();
  {
    const int o = tid;
    float acc[16];
    float bv = b1[o];
    #pragma unroll
    for (int i=0;i<16;++i) acc[i] = bv;
    for (int k=0;k<128;k+=4){
      float w0=w1[(k+0)*128+o], w1v=w1[(k+1)*128+o], w2v=w1[(k+2)*128+o], w3v=w1[(k+3)*128+o];
      #pragma unroll
      for (int i=0;i<16;++i){
        float4 hv = *(const float4*)&ht[i][k];
        acc[i] += hv.x*w0 + hv.y*w1v + hv.z*w2v + hv.w*w3v;
      }
    }
    #pragma unroll
    for (int i=0;i<16;++i) s1[i][o] = silu_f(acc[i]);
  }
  __syncthreads();
  {
    const int o = tid & 63;
    const int hf = tid >> 6;          // two halves: nodes 0-7 / 8-15
    float acc[8];
    float bv = b2[o];
    #pragma unroll
    for (int i=0;i<8;++i) acc[i] = bv;
    for (int k=0;k<128;k+=4){
      float w0=w2[(k+0)*64+o], w1v=w2[(k+1)*64+o], w2v=w2[(k+2)*64+o], w3v=w2[(k+3)*64+o];
      #pragma unroll
      for (int i=0;i<8;++i){
        float4 sv = *(const float4*)&s1[hf*8+i][k];
        acc[i] += sv.x*w0 + sv.y*w1v + sv.z*w2v + sv.w*w3v;
      }
    }
    #pragma unroll
    for (int i=0;i<8;++i) s2[hf*8+i][o] = silu_f(acc[i]);
  }
  __syncthreads();
  // THE r1-r5 BUG WAS HERE: "if (tid < 144)" with blockDim=128 left 16/144
  // outputs per block unwritten (= the constant 1.84375 absmax). Loop instead.
  for (int idx = tid; idx < 144; idx += 128){
    int i = idx/9, oo = idx%9;
    float a = b3[oo];
    #pragma unroll 8
    for (int k=0;k<64;++k) a += s2[i][k]*w3[k*9+oo];
    out[(size_t)(n0+i)*9 + oo] = a;
  }
}

// ---------------- workspace layout (26,284,288 B) ----------------
constexpr size_t OFF_W1P  = 0;                        // 6*36864*2 = 442,368 B
constexpr size_t OFF_H    = 524288;                   // N*128*4 = 10,240,000 B
constexpr size_t OFF_HH   = OFF_H   + 10240000;       // N*128*2 =  5,120,000 B
constexpr size_t OFF_S    = OFF_HH  + 5120000;        // N*128*4 = 10,240,000 B
constexpr size_t OFF_INVD = OFF_S   + 10240000;       // N*4
constexpr size_t OFF_DEG  = OFF_INVD + 80000;         // N*4
constexpr size_t WS_NEEDED= OFF_DEG + 80000;

extern "C" void kernel_launch(void* const* d_in, const int* in_sizes, int n_in,
                              void* d_out, int out_size, void* d_ws, size_t ws_size,
                              hipStream_t stream)
{
  float* out = (float*)d_out;
  const int nout_blk = (out_size + 255)/256;

  // host-side guards (validated clean in r5; keep as cheap regression tripwires)
  static const int EXP_SIZES[17] = {280000,640000,960000,1792,128,16384,128,
                                    198912,768,98304,768,16384,128,8192,64,576,9};
  if (n_in != 17){
    sentinel_kernel<<<nout_blk, 256, 0, stream>>>(out, out_size, 2.0e7f + (float)n_in*1.0e3f);
    return;
  }
  for (int i = 0; i < 17; ++i){
    if (in_sizes[i] != EXP_SIZES[i]){
      int sz = in_sizes[i] < 99999 ? in_sizes[i] : 99999;
      sentinel_kernel<<<nout_blk, 256, 0, stream>>>(out, out_size,
          1.0e7f + (float)i*1.0e5f + (float)sz);
      return;
    }
  }
  if (ws_size < WS_NEEDED){
    sentinel_kernel<<<nout_blk, 256, 0, stream>>>(out, out_size, 1.0e6f);
    return;
  }

  const float* x       = (const float*)d_in[0];
  const int*   ei      = (const int*)  d_in[1];
  const float* eattr   = (const float*)d_in[2];
  const float* enc_w1  = (const float*)d_in[3];
  const float* enc_b1  = (const float*)d_in[4];
  const float* enc_w2  = (const float*)d_in[5];
  const float* enc_b2  = (const float*)d_in[6];
  const float* conv_w1 = (const float*)d_in[7];
  const float* conv_b1 = (const float*)d_in[8];
  const float* conv_w2 = (const float*)d_in[9];
  const float* conv_b2 = (const float*)d_in[10];
  const float* dec_w1  = (const float*)d_in[11];
  const float* dec_b1  = (const float*)d_in[12];
  const float* dec_w2  = (const float*)d_in[13];
  const float* dec_b2  = (const float*)d_in[14];
  const float* dec_w3  = (const float*)d_in[15];
  const float* dec_b3  = (const float*)d_in[16];

  char* ws = (char*)d_ws;
  _Float16* w1p  = (_Float16*)(ws + OFF_W1P);
  float*    h    = (float*)   (ws + OFF_H);
  _Float16* hh   = (_Float16*)(ws + OFF_HH);
  float*    S    = (float*)   (ws + OFF_S);
  float*    invd = (float*)   (ws + OFF_INVD);
  float*    deg  = (float*)   (ws + OFF_DEG);

  hipMemsetAsync(S,   0, (size_t)NN*HD*sizeof(float), stream);
  hipMemsetAsync(deg, 0, (size_t)NN*sizeof(float), stream);

  pack_w1_kernel<<<864, 256, 0, stream>>>(conv_w1, w1p);
  deg_kernel<<<EE/256, 256, 0, stream>>>(ei, deg);
  invd_kernel<<<(NN+255)/256, 256, 0, stream>>>(deg, invd);
  encoder_kernel<<<NN/16, 128, 0, stream>>>(x, enc_w1, enc_b1, enc_w2, enc_b2, h, hh);
  for (int l=0; l<6; ++l){
    edge_kernel<<<EE/128, 256, 0, stream>>>(hh, ei, eattr,
                                            w1p + (size_t)l*36864,
                                            conv_b1 + (size_t)l*128, S);
    node_kernel<<<NN/16, 128, 0, stream>>>(conv_w2 + (size_t)l*16384,
                                           conv_b2 + (size_t)l*128,
                                           S, invd, h, hh);
  }
  decoder_kernel<<<NN/16, 128, 0, stream>>>(h, dec_w1, dec_b1, dec_w2, dec_b2,
                                            dec_w3, dec_b3, out);
}

// Round 7
// 1222.597 us; speedup vs baseline: 1.0613x; 1.0613x over previous
//
#include <hip/hip_runtime.h>
#include <hip/hip_bf16.h>

#define NN 20000
#define EE 320000
#define HD 128   // hidden

typedef _Float16 half8 __attribute__((ext_vector_type(8)));
typedef _Float16 half4 __attribute__((ext_vector_type(4)));
typedef float floatx4 __attribute__((ext_vector_type(4)));

__device__ __forceinline__ float silu_f(float x){ return x / (1.f + __expf(-x)); }

// edge_index dtype probe (int64-as-int32 has zero odd words); int32 on this harness.
__device__ __forceinline__ bool ei_is64(const int* __restrict__ ei){
  return (ei[1] | ei[3] | ei[5] | ei[7]) == 0;
}
__device__ __forceinline__ int ei_src(const int* __restrict__ ei, int e, bool is64){
  return is64 ? ei[2*(size_t)e] : ei[e];
}
__device__ __forceinline__ int ei_dst(const int* __restrict__ ei, int e, bool is64){
  return is64 ? ei[2*(size_t)EE + 2*(size_t)e] : ei[EE + e];
}

__global__ __launch_bounds__(256) void sentinel_kernel(float* __restrict__ out, int n, float val){
  int i = blockIdx.x*256 + threadIdx.x;
  if (i < n) out[i] = val;
}

// ---------------- W1 packing: MFMA B-fragment fp16 layout ----------------
// w1p[l*36864 + ((ks*8+cb)*64+lane)*8 + j] = W1[l][ks*32+(lane>>4)*8+j][cb*16+(lane&15)], 0 if k>=259
__global__ __launch_bounds__(256) void pack_w1_kernel(const float* __restrict__ w1,
                                                      _Float16* __restrict__ w1p){
  int idx = blockIdx.x*256 + threadIdx.x;      // 6*36864 = 221184 total
  int j    = idx & 7;
  int lane = (idx >> 3) & 63;
  int rest = idx >> 9;
  int cb   = rest & 7;
  int rest2= rest >> 3;
  int ks   = rest2 % 9;
  int l    = rest2 / 9;
  int k = ks*32 + (lane>>4)*8 + j;
  int n = cb*16 + (lane&15);
  float v = (k < 259) ? w1[(size_t)l*259*128 + (size_t)k*128 + n] : 0.f;
  w1p[idx] = (_Float16)v;
}

// ---------------- CSR build ----------------
__global__ __launch_bounds__(256) void count_kernel(const int* __restrict__ ei, int* __restrict__ cnt){
  int e = blockIdx.x*256 + threadIdx.x;   // EE/256 exact
  bool is64 = ei_is64(ei);
  atomicAdd(&cnt[ei_dst(ei, e, is64)], 1);
}

// single block, 1024 threads: exclusive scan of cnt -> row_start; cnt buffer becomes cursor; invd
__global__ __launch_bounds__(1024) void scan_kernel(int* __restrict__ cntcur,
                                                    int* __restrict__ row_start,
                                                    float* __restrict__ invd){
  __shared__ int part[1024];
  const int t = threadIdx.x;
  const int base = t*20;
  int loc[20];
  int sum = 0;
  #pragma unroll
  for (int i=0;i<20;++i){
    int n = base+i;
    int v = (n < NN) ? cntcur[n] : 0;
    loc[i] = sum; sum += v;
  }
  part[t] = sum;
  __syncthreads();
  for (int off=1; off<1024; off<<=1){
    int v = (t >= off) ? part[t-off] : 0;
    __syncthreads();
    part[t] += v;
    __syncthreads();
  }
  int pre = (t > 0) ? part[t-1] : 0;
  #pragma unroll
  for (int i=0;i<20;++i){
    int n = base+i;
    if (n < NN){
      int rs = pre + loc[i];
      int deg = ((i<19)?loc[i+1]:sum) - loc[i];
      row_start[n] = rs;
      invd[n] = (deg > 0) ? 1.f/(float)deg : 0.f;
      cntcur[n] = rs;      // cursor init (own indices only; safe)
    }
  }
  if (t == 1023) row_start[NN] = part[1023];
}

__global__ __launch_bounds__(256) void scatter_kernel(const int* __restrict__ ei,
                                                      const float* __restrict__ eattr,
                                                      int* __restrict__ cur,
                                                      int* __restrict__ src_s,
                                                      _Float16* __restrict__ ea_s){
  int e = blockIdx.x*256 + threadIdx.x;   // EE/256 exact
  bool is64 = ei_is64(ei);
  int s = ei_src(ei, e, is64);
  int d = ei_dst(ei, e, is64);
  int pos = atomicAdd(&cur[d], 1);
  src_s[pos] = s;
  half4 ea;
  ea[0] = (_Float16)eattr[(size_t)e*3+0];
  ea[1] = (_Float16)eattr[(size_t)e*3+1];
  ea[2] = (_Float16)eattr[(size_t)e*3+2];
  ea[3] = (_Float16)0.f;
  *(half4*)(ea_s + (size_t)pos*4) = ea;
}

// ---------------- encoder: x(N,14) -> h(N,128) fp32 + fp16 ----------------
__global__ __launch_bounds__(128) void encoder_kernel(
    const float* __restrict__ x, const float* __restrict__ w1, const float* __restrict__ b1,
    const float* __restrict__ w2, const float* __restrict__ b2,
    float* __restrict__ h, _Float16* __restrict__ hh)
{
  __shared__ float xs[16][14];
  __shared__ float s1[16][128];
  const int n0 = blockIdx.x*16;
  const int tid = threadIdx.x;
  for (int idx=tid; idx<224; idx+=128){
    int i = idx/14, k = idx%14;
    xs[i][k] = x[(size_t)(n0+i)*14 + k];
  }
  __syncthreads();
  const int o = tid;
  float acc[16];
  float bv = b1[o];
  #pragma unroll
  for (int i=0;i<16;++i) acc[i] = bv;
  for (int k=0;k<14;++k){
    float w = w1[k*128+o];
    #pragma unroll
    for (int i=0;i<16;++i) acc[i] += xs[i][k]*w;
  }
  #pragma unroll
  for (int i=0;i<16;++i) s1[i][o] = silu_f(acc[i]);
  __syncthreads();
  float bv2 = b2[o];
  #pragma unroll
  for (int i=0;i<16;++i) acc[i] = bv2;
  for (int k=0;k<128;k+=4){
    float w0=w2[(k+0)*128+o], w1v=w2[(k+1)*128+o], w2v=w2[(k+2)*128+o], w3v=w2[(k+3)*128+o];
    #pragma unroll
    for (int i=0;i<16;++i){
      float4 sv = *(const float4*)&s1[i][k];
      acc[i] += sv.x*w0 + sv.y*w1v + sv.z*w2v + sv.w*w3v;
    }
  }
  #pragma unroll
  for (int i=0;i<16;++i){
    size_t off = (size_t)(n0+i)*HD + o;
    h[off] = acc[i];
    hh[off] = (_Float16)acc[i];
  }
}

// ---------------- edge kernel (CSR): per dst-node message GEMM + in-register mean ----------------
// block = 256 = 4 waves; each wave owns 2 consecutive dst nodes, loops 16-edge chunks.
// No atomics: each node's S row written by exactly one wave. S := mean(silu(...)) directly.
__global__ __launch_bounds__(256) void edge_csr_kernel(
    const _Float16* __restrict__ hh, const int* __restrict__ row_start,
    const int* __restrict__ src_s, const _Float16* __restrict__ ea_s,
    const _Float16* __restrict__ w1p, const float* __restrict__ b1,
    const float* __restrict__ invd, float* __restrict__ S)
{
  const int tid = threadIdx.x;
  const int wv  = tid >> 6;
  const int ln  = tid & 63;
  const int q   = ln >> 4;
  const int m   = ln & 15;
  const int n0  = blockIdx.x*8 + wv*2;    // grid = NN/8 = 2500, exact
  const int n1  = n0 + 1;
  const int rs0 = row_start[n0], re0 = row_start[n0+1];
  const int rs1 = row_start[n1], re1 = row_start[n1+1];
  const int nch0 = (re0 - rs0 + 15) >> 4;
  const int nch1 = (re1 - rs1 + 15) >> 4;
  const int nch  = nch0 > nch1 ? nch0 : nch1;

  float bv[8];
  #pragma unroll
  for (int cb=0;cb<8;++cb) bv[cb] = b1[cb*16 + m];

  float pl0[8], pl1[8];
  #pragma unroll
  for (int cb=0;cb<8;++cb){ pl0[cb] = 0.f; pl1[cb] = 0.f; }

  const int clamp0 = (re0 > 0) ? re0 - 1 : 0;
  const int clamp1 = (re1 > 0) ? re1 - 1 : 0;

  for (int c = 0; c < nch; ++c){
    // src indices for this lane's A-row m
    int p0 = rs0 + c*16 + m;
    int p1 = rs1 + c*16 + m;
    int pc0 = p0 < clamp0 ? p0 : clamp0;
    int pc1 = p1 < clamp1 ? p1 : clamp1;
    const int s0 = src_s[pc0];
    const int s1 = src_s[pc1];

    floatx4 acc0[8], acc1[8];
    #pragma unroll
    for (int cb=0;cb<8;++cb){ acc0[cb] = (floatx4){0,0,0,0}; acc1[cb] = (floatx4){0,0,0,0}; }

    // K-phase 1: h_dst (k 0..127) — row-uniform broadcast loads
    #pragma unroll
    for (int ks=0; ks<4; ++ks){
      half8 a0 = *(const half8*)(hh + (size_t)n0*HD + ks*32 + q*8);
      half8 a1 = *(const half8*)(hh + (size_t)n1*HD + ks*32 + q*8);
      const _Float16* wb = w1p + (size_t)(ks*8*64 + ln)*8;
      #pragma unroll
      for (int cb=0; cb<8; ++cb){
        half8 b = *(const half8*)(wb + cb*512);
        acc0[cb] = __builtin_amdgcn_mfma_f32_16x16x32_f16(a0, b, acc0[cb], 0,0,0);
        acc1[cb] = __builtin_amdgcn_mfma_f32_16x16x32_f16(a1, b, acc1[cb], 0,0,0);
      }
    }
    // K-phase 2: h_src (k 128..255) — per-row gather
    #pragma unroll
    for (int ks=4; ks<8; ++ks){
      half8 a0 = *(const half8*)(hh + (size_t)s0*HD + (ks-4)*32 + q*8);
      half8 a1 = *(const half8*)(hh + (size_t)s1*HD + (ks-4)*32 + q*8);
      const _Float16* wb = w1p + (size_t)(ks*8*64 + ln)*8;
      #pragma unroll
      for (int cb=0; cb<8; ++cb){
        half8 b = *(const half8*)(wb + cb*512);
        acc0[cb] = __builtin_amdgcn_mfma_f32_16x16x32_f16(a0, b, acc0[cb], 0,0,0);
        acc1[cb] = __builtin_amdgcn_mfma_f32_16x16x32_f16(a1, b, acc1[cb], 0,0,0);
      }
    }
    // K-phase 3: edge_attr tail (k 256..287)
    {
      half8 a0, a1;
      #pragma unroll
      for (int j=0;j<8;++j){ a0[j] = (_Float16)0.f; a1[j] = (_Float16)0.f; }
      if (q == 0){
        half4 e0 = *(const half4*)(ea_s + (size_t)pc0*4);
        half4 e1 = *(const half4*)(ea_s + (size_t)pc1*4);
        a0[0]=e0[0]; a0[1]=e0[1]; a0[2]=e0[2]; a0[3]=e0[3];
        a1[0]=e1[0]; a1[1]=e1[1]; a1[2]=e1[2]; a1[3]=e1[3];
      }
      const _Float16* wb = w1p + (size_t)(8*8*64 + ln)*8;
      #pragma unroll
      for (int cb=0; cb<8; ++cb){
        half8 b = *(const half8*)(wb + cb*512);
        acc0[cb] = __builtin_amdgcn_mfma_f32_16x16x32_f16(a0, b, acc0[cb], 0,0,0);
        acc1[cb] = __builtin_amdgcn_mfma_f32_16x16x32_f16(a1, b, acc1[cb], 0,0,0);
      }
    }
    // per-chunk epilogue: silu + masked row accumulation (C row = q*4+r, col = cb*16+m)
    #pragma unroll
    for (int cb=0; cb<8; ++cb){
      #pragma unroll
      for (int r=0;r<4;++r){
        int row = q*4 + r;
        if (rs0 + c*16 + row < re0) pl0[cb] += silu_f(acc0[cb][r] + bv[cb]);
        if (rs1 + c*16 + row < re1) pl1[cb] += silu_f(acc1[cb][r] + bv[cb]);
      }
    }
  }

  // cross-quad butterfly: lanes m, m+16, m+32, m+48 hold the 4 row-groups of col cb*16+m
  #pragma unroll
  for (int cb=0; cb<8; ++cb){
    pl0[cb] += __shfl_xor(pl0[cb], 16);
    pl0[cb] += __shfl_xor(pl0[cb], 32);
    pl1[cb] += __shfl_xor(pl1[cb], 16);
    pl1[cb] += __shfl_xor(pl1[cb], 32);
  }
  // store mean: lane (q,m) writes cols q*32+m and q*32+16+m  (cb = 2q, 2q+1)
  const float iv0 = invd[n0], iv1 = invd[n1];
  S[(size_t)n0*HD + q*32 + m]      = pl0[2*q]   * iv0;
  S[(size_t)n0*HD + q*32 + 16 + m] = pl0[2*q+1] * iv0;
  S[(size_t)n1*HD + q*32 + m]      = pl1[2*q]   * iv1;
  S[(size_t)n1*HD + q*32 + 16 + m] = pl1[2*q+1] * iv1;
}

// ---------------- node update: h += S·W2 + b2 (S already the mean), refresh hh ----------------
__global__ __launch_bounds__(128) void node_kernel(
    const float* __restrict__ w2, const float* __restrict__ b2,
    const float* __restrict__ S, const float* __restrict__ invd,
    float* __restrict__ h, _Float16* __restrict__ hh)
{
  __shared__ float t[16][128];
  const int n0 = blockIdx.x*16;
  const int tid = threadIdx.x;
  for (int idx=tid; idx<2048; idx+=128){
    int i = idx >> 7, k = idx & 127;
    t[i][k] = S[(size_t)(n0+i)*HD + k];
  }
  __syncthreads();
  const int o = tid;
  float acc[16];
  const float bv = b2[o];
  #pragma unroll
  for (int i=0;i<16;++i) acc[i] = (invd[n0+i] > 0.f) ? bv : 0.f;
  for (int k=0;k<128;k+=4){
    float w0 = w2[(k+0)*128+o];
    float w1v= w2[(k+1)*128+o];
    float w2v= w2[(k+2)*128+o];
    float w3v= w2[(k+3)*128+o];
    #pragma unroll
    for (int i=0;i<16;++i){
      float4 tv = *(const float4*)&t[i][k];
      acc[i] += tv.x*w0 + tv.y*w1v + tv.z*w2v + tv.w*w3v;
    }
  }
  #pragma unroll
  for (int i=0;i<16;++i){
    size_t off = (size_t)(n0+i)*HD + o;
    float hv = h[off] + acc[i];
    h[off] = hv;
    hh[off] = (_Float16)hv;
  }
}

// ---------------- decoder: 128 ->(silu) 128 ->(silu) 64 -> 9 ----------------
__global__ __launch_bounds__(128) void decoder_kernel(
    const float* __restrict__ h,
    const float* __restrict__ w1, const float* __restrict__ b1,
    const float* __restrict__ w2, const float* __restrict__ b2,
    const float* __restrict__ w3, const float* __restrict__ b3,
    float* __restrict__ out)
{
  __shared__ float ht[16][128];
  __shared__ float s1[16][128];
  __shared__ float s2[16][64];
  const int n0 = blockIdx.x*16;
  const int tid = threadIdx.x;
  for (int idx=tid; idx<2048; idx+=128){
    int i = idx>>7, k = idx&127;
    ht[i][k] = h[(size_t)(n0+i)*HD + k];
  }
  __syncthreads();
  {
    const int o = tid;
    float acc[16];
    float bv = b1[o];
    #pragma unroll
    for (int i=0;i<16;++i) acc[i] = bv;
    for (int k=0;k<128;k+=4){
      float w0=w1[(k+0)*128+o], w1v=w1[(k+1)*128+o], w2v=w1[(k+2)*128+o], w3v=w1[(k+3)*128+o];
      #pragma unroll
      for (int i=0;i<16;++i){
        float4 hv = *(const float4*)&ht[i][k];
        acc[i] += hv.x*w0 + hv.y*w1v + hv.z*w2v + hv.w*w3v;
      }
    }
    #pragma unroll
    for (int i=0;i<16;++i) s1[i][o] = silu_f(acc[i]);
  }
  __syncthreads();
  {
    const int o = tid & 63;
    const int hf = tid >> 6;
    float acc[8];
    float bv = b2[o];
    #pragma unroll
    for (int i=0;i<8;++i) acc[i] = bv;
    for (int k=0;k<128;k+=4){
      float w0=w2[(k+0)*64+o], w1v=w2[(k+1)*64+o], w2v=w2[(k+2)*64+o], w3v=w2[(k+3)*64+o];
      #pragma unroll
      for (int i=0;i<8;++i){
        float4 sv = *(const float4*)&s1[hf*8+i][k];
        acc[i] += sv.x*w0 + sv.y*w1v + sv.z*w2v + sv.w*w3v;
      }
    }
    #pragma unroll
    for (int i=0;i<8;++i) s2[hf*8+i][o] = silu_f(acc[i]);
  }
  __syncthreads();
  // loop (NOT "if (tid<144)") — the r1-r5 bug
  for (int idx = tid; idx < 144; idx += 128){
    int i = idx/9, oo = idx%9;
    float a = b3[oo];
    #pragma unroll 8
    for (int k=0;k<64;++k) a += s2[i][k]*w3[k*9+oo];
    out[(size_t)(n0+i)*9 + oo] = a;
  }
}

// ---------------- workspace layout (30,204,352 B) ----------------
constexpr size_t OFF_W1P  = 0;                         // 442,368 -> pad
constexpr size_t OFF_H    = 524288;                    // +10,240,000
constexpr size_t OFF_HH   = OFF_H   + 10240000;        // +5,120,000
constexpr size_t OFF_S    = OFF_HH  + 5120000;         // +10,240,000
constexpr size_t OFF_INVD = OFF_S   + 10240000;        // +80,000
constexpr size_t OFF_RS   = OFF_INVD + 80000;          // row_start: (NN+1)*4 -> 80,064
constexpr size_t OFF_CUR  = OFF_RS  + 80064;           // cnt/cursor +80,000
constexpr size_t OFF_SRC  = OFF_CUR + 80000;           // src_s: EE*4 = 1,280,000
constexpr size_t OFF_EA   = OFF_SRC + 1280000;         // ea_s: EE*4*2 = 2,560,000
constexpr size_t WS_NEEDED= OFF_EA  + 2560000;

extern "C" void kernel_launch(void* const* d_in, const int* in_sizes, int n_in,
                              void* d_out, int out_size, void* d_ws, size_t ws_size,
                              hipStream_t stream)
{
  float* out = (float*)d_out;
  const int nout_blk = (out_size + 255)/256;

  static const int EXP_SIZES[17] = {280000,640000,960000,1792,128,16384,128,
                                    198912,768,98304,768,16384,128,8192,64,576,9};
  if (n_in != 17){
    sentinel_kernel<<<nout_blk, 256, 0, stream>>>(out, out_size, 2.0e7f + (float)n_in*1.0e3f);
    return;
  }
  for (int i = 0; i < 17; ++i){
    if (in_sizes[i] != EXP_SIZES[i]){
      int sz = in_sizes[i] < 99999 ? in_sizes[i] : 99999;
      sentinel_kernel<<<nout_blk, 256, 0, stream>>>(out, out_size,
          1.0e7f + (float)i*1.0e5f + (float)sz);
      return;
    }
  }
  if (ws_size < WS_NEEDED){
    sentinel_kernel<<<nout_blk, 256, 0, stream>>>(out, out_size, 1.0e6f);
    return;
  }

  const float* x       = (const float*)d_in[0];
  const int*   ei      = (const int*)  d_in[1];
  const float* eattr   = (const float*)d_in[2];
  const float* enc_w1  = (const float*)d_in[3];
  const float* enc_b1  = (const float*)d_in[4];
  const float* enc_w2  = (const float*)d_in[5];
  const float* enc_b2  = (const float*)d_in[6];
  const float* conv_w1 = (const float*)d_in[7];
  const float* conv_b1 = (const float*)d_in[8];
  const float* conv_w2 = (const float*)d_in[9];
  const float* conv_b2 = (const float*)d_in[10];
  const float* dec_w1  = (const float*)d_in[11];
  const float* dec_b1  = (const float*)d_in[12];
  const float* dec_w2  = (const float*)d_in[13];
  const float* dec_b2  = (const float*)d_in[14];
  const float* dec_w3  = (const float*)d_in[15];
  const float* dec_b3  = (const float*)d_in[16];

  char* ws = (char*)d_ws;
  _Float16* w1p   = (_Float16*)(ws + OFF_W1P);
  float*    h     = (float*)   (ws + OFF_H);
  _Float16* hh    = (_Float16*)(ws + OFF_HH);
  float*    S     = (float*)   (ws + OFF_S);
  float*    invd  = (float*)   (ws + OFF_INVD);
  int*      rstart= (int*)     (ws + OFF_RS);
  int*      cur   = (int*)     (ws + OFF_CUR);
  int*      src_s = (int*)     (ws + OFF_SRC);
  _Float16* ea_s  = (_Float16*)(ws + OFF_EA);

  hipMemsetAsync(cur, 0, (size_t)NN*sizeof(int), stream);

  pack_w1_kernel<<<864, 256, 0, stream>>>(conv_w1, w1p);
  count_kernel<<<EE/256, 256, 0, stream>>>(ei, cur);
  scan_kernel<<<1, 1024, 0, stream>>>(cur, rstart, invd);
  scatter_kernel<<<EE/256, 256, 0, stream>>>(ei, eattr, cur, src_s, ea_s);
  encoder_kernel<<<NN/16, 128, 0, stream>>>(x, enc_w1, enc_b1, enc_w2, enc_b2, h, hh);
  for (int l=0; l<6; ++l){
    edge_csr_kernel<<<NN/8, 256, 0, stream>>>(hh, rstart, src_s, ea_s,
                                              w1p + (size_t)l*36864,
                                              conv_b1 + (size_t)l*128, invd, S);
    node_kernel<<<NN/16, 128, 0, stream>>>(conv_w2 + (size_t)l*16384,
                                           conv_b2 + (size_t)l*128,
                                           S, invd, h, hh);
  }
  decoder_kernel<<<NN/16, 128, 0, stream>>>(h, dec_w1, dec_b1, dec_w2, dec_b2,
                                            dec_w3, dec_b3, out);
}